// Round 1
// baseline (2473.643 us; speedup 1.0000x reference)
//
#include <hip/hip_runtime.h>

#define NE   256000
#define NN   20000
#define NC   32
#define NF   32
#define EPB  32
#define TPB  256

// ---------------- compile-time real Clebsch-Gordan tables ----------------
namespace cg {

constexpr double cfact(int n){ double r=1.0; for(int i=2;i<=n;++i) r*=(double)i; return r; }
constexpr double cabsd(double x){ return x<0.0?-x:x; }
constexpr double csqrt(double x){
  if(x<=0.0) return 0.0;
  double g = x<1.0 ? 1.0 : x;
  for(int i=0;i<100;++i) g = 0.5*(g + x/g);
  return g;
}
constexpr double cw3j(int j1,int j2,int j3,int m1,int m2,int m3){
  if(m1+m2+m3!=0) return 0.0;
  int dj = j1-j2; int adj = dj<0?-dj:dj;
  if(j3<adj || j3>j1+j2) return 0.0;
  int t1=j2-m1-j3, t2=j1+m2-j3, t3=j1+j2-j3, t4=j1-m1, t5=j2+m2;
  int tmin = 0; if(t1>tmin)tmin=t1; if(t2>tmin)tmin=t2;
  int tmax = t3; if(t4<tmax)tmax=t4; if(t5<tmax)tmax=t5;
  double s=0.0;
  for(int t=tmin;t<=tmax;++t){
    double d = cfact(t)*cfact(t-t1)*cfact(t-t2)*cfact(t3-t)*cfact(t4-t)*cfact(t5-t);
    s += ((t&1)? -1.0:1.0)/d;
  }
  double delta = cfact(j1+j2-j3)*cfact(j1-j2+j3)*cfact(-j1+j2+j3)/cfact(j1+j2+j3+1);
  double norm = csqrt(delta*cfact(j1+m1)*cfact(j1-m1)*cfact(j2+m2)*cfact(j2-m2)*cfact(j3+m3)*cfact(j3-m3));
  int e = j1-j2-m3;
  double ph = (e%2!=0)? -1.0 : 1.0;
  return ph*norm*s;
}
struct KD { double re, im; };
struct UM { KD m[5][5]; };
constexpr UM u_real(int l){
  UM U{};
  U.m[l][l] = KD{1.0,0.0};
  double s2 = 0.70710678118654752440;
  for(int mm=1;mm<=l;++mm){
    double sg = (mm&1)? -1.0:1.0;
    U.m[l+mm][l+mm] = KD{sg*s2, 0.0};
    U.m[l+mm][l-mm] = KD{s2, 0.0};
    U.m[l-mm][l+mm] = KD{0.0, -sg*s2};
    U.m[l-mm][l-mm] = KD{0.0, s2};
  }
  return U;
}
struct T3 { double v[5][5][5]; };
constexpr T3 real_cg(int l1,int l2,int l3){
  KD T[5][5][5]{};
  UM U1=u_real(l1), U2=u_real(l2), U3=u_real(l3);
  for(int m1=-l1;m1<=l1;++m1)
  for(int m2=-l2;m2<=l2;++m2){
    int m3 = -(m1+m2);
    if(m3<-l3 || m3>l3) continue;
    double w = cw3j(l1,l2,l3,m1,m2,m3);
    if(w==0.0) continue;
    for(int a=0;a<2*l1+1;++a){
      KD u1 = U1.m[a][l1+m1];
      if(u1.re==0.0 && u1.im==0.0) continue;
      for(int b=0;b<2*l2+1;++b){
        KD u2 = U2.m[b][l2+m2];
        if(u2.re==0.0 && u2.im==0.0) continue;
        KD u12 = KD{u1.re*u2.re - u1.im*u2.im, u1.re*u2.im + u1.im*u2.re};
        for(int c=0;c<2*l3+1;++c){
          KD u3 = U3.m[c][l3+m3];
          if(u3.re==0.0 && u3.im==0.0) continue;
          KD u123 = KD{u12.re*u3.re - u12.im*u3.im, u12.re*u3.im + u12.im*u3.re};
          T[a][b][c].re += u123.re*w;
          T[a][b][c].im += u123.im*w;
        }
      }
    }
  }
  double mr=0.0, mi=0.0;
  for(int a=0;a<5;++a)for(int b=0;b<5;++b)for(int c=0;c<5;++c){
    if(cabsd(T[a][b][c].re)>mr) mr=cabsd(T[a][b][c].re);
    if(cabsd(T[a][b][c].im)>mi) mi=cabsd(T[a][b][c].im);
  }
  T3 R{};
  for(int a=0;a<5;++a)for(int b=0;b<5;++b)for(int c=0;c<5;++c)
    R.v[a][b][c] = (mr>=mi)? T[a][b][c].re : T[a][b][c].im;
  return R;
}
constexpr int MAXE = 320;
struct List { int n; int p[MAXE]; int a[MAXE]; int b[MAXE]; int c[MAXE]; float v[MAXE]; };
constexpr List build(){
  List L{};
  const int PMP[11][3]={{0,0,0},{1,1,0},{2,2,0},{0,1,1},{1,0,1},{1,2,1},{2,1,1},{0,2,2},{1,1,2},{2,0,2},{2,2,2}};
  const int LOFF[3]={0,1,4};
  const int NP[3]={3,4,4};
  for(int p=0;p<11;++p){
    int l1=PMP[p][0], l2=PMP[p][1], l3=PMP[p][2];
    T3 T = real_cg(l1,l2,l3);
    double fac = csqrt((2.0*l3+1.0)/(double)NP[l3]);  // sqrt(2l3+1) from _tp, /sqrt(npaths) from mixes
    for(int a=0;a<2*l1+1;++a)for(int b=0;b<2*l2+1;++b)for(int c=0;c<2*l3+1;++c){
      double v = T.v[a][b][c];
      if((v>1e-12 || v<-1e-12) && L.n < MAXE){
        L.p[L.n]=p; L.a[L.n]=LOFF[l1]+a; L.b[L.n]=LOFF[l2]+b; L.c[L.n]=LOFF[l3]+c;
        L.v[L.n]=(float)(v*fac);
        L.n++;
      }
    }
  }
  return L;
}
constexpr List CGL = build();
static_assert(CGL.n > 0 && CGL.n < MAXE, "CG table overflow/empty");
} // namespace cg

// Unrolled CG contraction: acc[c] += w[p]*v * x[a]*y[b]; all indices compile-time.
template<int K>
__device__ __forceinline__ void cg_accum(float* acc, const float* w, const float* x, const float* y){
  if constexpr (K < cg::CGL.n){
    constexpr int   p  = cg::CGL.p[K];
    constexpr int   a  = cg::CGL.a[K];
    constexpr int   b  = cg::CGL.b[K];
    constexpr int   cc = cg::CGL.c[K];
    constexpr float v  = cg::CGL.v[K];
    acc[cc] = fmaf(w[p]*v, x[a]*y[b], acc[cc]);
    cg_accum<K+1>(acc, w, x, y);
  }
}

// ---------------- kernels ----------------

__global__ __launch_bounds__(TPB) void init_out_kernel(const float4* __restrict__ src,
                                                       float4* __restrict__ dst, int n4){
  int i = blockIdx.x*TPB + threadIdx.x;
  if(i < n4) dst[i] = src[i];
}

__global__ __launch_bounds__(TPB) void edge_kernel(
  const float* __restrict__ nodes_snd, const int* __restrict__ edge_ind,
  const float* __restrict__ Y_edge,    const float* __restrict__ dist_feat,
  const float* __restrict__ w0a, const float* __restrict__ w1a, const float* __restrict__ w2a,
  const float* __restrict__ b0a, const float* __restrict__ ka,
  const float* __restrict__ cmWa, const float* __restrict__ cmba,
  const float* __restrict__ w0b, const float* __restrict__ w1b, const float* __restrict__ w2b,
  const float* __restrict__ b0b, const float* __restrict__ kb,
  const float* __restrict__ cmWb, const float* __restrict__ cmbb,
  const float* __restrict__ Wda, const float* __restrict__ bda,
  const float* __restrict__ Wdb, const float* __restrict__ bdb,
  float* __restrict__ out)
{
  __shared__ float sWa[NF][NC*3];    // 12 KB, lane stride 3  -> conflict-free
  __shared__ float sWb[NF][NC*11];   // 44 KB, lane stride 11 -> conflict-free
  __shared__ float sdist[EPB][NF];   // 4 KB
  __shared__ float ssma[EPB][9];
  __shared__ float ssmb[EPB][9];

  const int t = threadIdx.x;
  const int c = t & 31;        // channel
  const int g = t >> 5;        // edge group 0..7 ; thread handles edges g, g+8, g+16, g+24
  const int eb = blockIdx.x * EPB;

  // stage weight matrices (layouts identical to global, flat copy, float4)
  {
    float4* dA = (float4*)&sWa[0][0]; const float4* gA = (const float4*)Wda;
    for(int i=t;i<NF*NC*3/4;i+=TPB) dA[i] = gA[i];
    float4* dB = (float4*)&sWb[0][0]; const float4* gB = (const float4*)Wdb;
    for(int i=t;i<NF*NC*11/4;i+=TPB) dB[i] = gB[i];
  }
  // stage dist_feat tile
  #pragma unroll
  for(int i=0;i<4;++i){ int el=g+i*8; sdist[el][c] = dist_feat[(eb+el)*NF + c]; }

  // per-edge selfmix (threads 0..31: branch a, 32..63: branch b)
  if(t < 64){
    const int el = t & 31;
    const float* yp = Y_edge + (size_t)(eb+el)*9;
    float Y[9];
    #pragma unroll
    for(int m=0;m<9;++m) Y[m]=yp[m];
    float ws[11]; const float* b0; const float* kk; float* dst;
    if(t < 32){
      ws[0]=w0a[0];ws[1]=w0a[1];ws[2]=w0a[2];
      ws[3]=w1a[0];ws[4]=w1a[1];ws[5]=w1a[2];ws[6]=w1a[3];
      ws[7]=w2a[0];ws[8]=w2a[1];ws[9]=w2a[2];ws[10]=w2a[3];
      b0=b0a; kk=ka; dst=ssma[el];
    } else {
      ws[0]=w0b[0];ws[1]=w0b[1];ws[2]=w0b[2];
      ws[3]=w1b[0];ws[4]=w1b[1];ws[5]=w1b[2];ws[6]=w1b[3];
      ws[7]=w2b[0];ws[8]=w2b[1];ws[9]=w2b[2];ws[10]=w2b[3];
      b0=b0b; kk=kb; dst=ssmb[el];
    }
    float z[9];
    #pragma unroll
    for(int m=0;m<9;++m) z[m]=0.f;
    cg_accum<0>(z, ws, Y, Y);
    z[0] += b0[0];
    float k0=kk[0], k1=kk[1], k2=kk[2];
    z[0]+=k0*Y[0];
    z[1]+=k1*Y[1]; z[2]+=k1*Y[2]; z[3]+=k1*Y[3];
    z[4]+=k2*Y[4]; z[5]+=k2*Y[5]; z[6]+=k2*Y[6]; z[7]+=k2*Y[7]; z[8]+=k2*Y[8];
    #pragma unroll
    for(int m=0;m<9;++m) dst[m]=z[m];
  }
  __syncthreads();

  // ---- GEMM: wa[e][3], wb[e][11] = dist_feat[e] @ Wd + bias, 4 edges per thread ----
  float wa[4][3], wb[4][11];
  #pragma unroll
  for(int i=0;i<4;++i){
    #pragma unroll
    for(int l=0;l<3;++l)  wa[i][l] = bda[c*3+l];
    #pragma unroll
    for(int j=0;j<11;++j) wb[i][j] = bdb[c*11+j];
  }
  #pragma unroll 4
  for(int f=0;f<NF;++f){
    float d0=sdist[g][f], d1=sdist[g+8][f], d2=sdist[g+16][f], d3=sdist[g+24][f];
    #pragma unroll
    for(int l=0;l<3;++l){
      float w = sWa[f][c*3+l];
      wa[0][l]=fmaf(d0,w,wa[0][l]); wa[1][l]=fmaf(d1,w,wa[1][l]);
      wa[2][l]=fmaf(d2,w,wa[2][l]); wa[3][l]=fmaf(d3,w,wa[3][l]);
    }
    #pragma unroll
    for(int j=0;j<11;++j){
      float w = sWb[f][c*11+j];
      wb[0][j]=fmaf(d0,w,wb[0][j]); wb[1][j]=fmaf(d1,w,wb[1][j]);
      wb[2][j]=fmaf(d2,w,wb[2][j]); wb[3][j]=fmaf(d3,w,wb[3][j]);
    }
  }

  // ---- epilogue: gather sender, channel-mix, pair-mix, scatter-add ----
  const float cwa0=cmWa[c], cwa1=cmWa[NC+c], cwa2=cmWa[2*NC+c], cba=cmba[c];
  const float cwb0=cmWb[c], cwb1=cmWb[NC+c], cwb2=cmWb[2*NC+c], cbb=cmbb[c];

  #pragma unroll
  for(int i=0;i<4;++i){
    const int el = g + i*8;
    const int e  = eb + el;
    const int snd = edge_ind[2*e];
    const int rcv = edge_ind[2*e+1];
    const float* xp = nodes_snd + ((size_t)snd*NC + c)*9;
    float x[9];
    #pragma unroll
    for(int m=0;m<9;++m) x[m]=xp[m];
    float sa[9], sb[9];
    #pragma unroll
    for(int m=0;m<9;++m){ sa[m]=ssma[el][m]; sb[m]=ssmb[el][m]; }

    // Yb = channel-mixed selfmix-b
    float yb[9];
    yb[0]=fmaf(cwb0,sb[0],cbb);
    yb[1]=cwb1*sb[1]; yb[2]=cwb1*sb[2]; yb[3]=cwb1*sb[3];
    yb[4]=cwb2*sb[4]; yb[5]=cwb2*sb[5]; yb[6]=cwb2*sb[6]; yb[7]=cwb2*sb[7]; yb[8]=cwb2*sb[8];

    // branch a: acc[m] = (wa[l]*x0) * Ya[m]
    const float x0 = x[0];
    const float wa0 = wa[i][0]*x0, wa1 = wa[i][1]*x0, wa2 = wa[i][2]*x0;
    float acc[9];
    acc[0]=wa0*fmaf(cwa0,sa[0],cba);
    acc[1]=wa1*(cwa1*sa[1]); acc[2]=wa1*(cwa1*sa[2]); acc[3]=wa1*(cwa1*sa[3]);
    acc[4]=wa2*(cwa2*sa[4]); acc[5]=wa2*(cwa2*sa[5]); acc[6]=wa2*(cwa2*sa[6]);
    acc[7]=wa2*(cwa2*sa[7]); acc[8]=wa2*(cwa2*sa[8]);

    // branch b: pair_mix(neighbors, Yb, wb)
    cg_accum<0>(acc, wb[i], x, yb);

    float* op = out + ((size_t)rcv*NC + c)*9;
    #pragma unroll
    for(int m=0;m<9;++m) unsafeAtomicAdd(&op[m], acc[m]);
  }
}

// ---------------- launch ----------------
extern "C" void kernel_launch(void* const* d_in, const int* in_sizes, int n_in,
                              void* d_out, int out_size, void* d_ws, size_t ws_size,
                              hipStream_t stream) {
  const float* nodes_rec = (const float*)d_in[0];
  const float* nodes_snd = (const float*)d_in[1];
  const int*   edge_ind  = (const int*)  d_in[2];
  const float* Y_edge    = (const float*)d_in[3];
  const float* dist_feat = (const float*)d_in[4];
  const float* w0a=(const float*)d_in[5],  *w1a=(const float*)d_in[6],  *w2a=(const float*)d_in[7];
  const float* b0a=(const float*)d_in[8],  *ka =(const float*)d_in[9];
  const float* cmWa=(const float*)d_in[10],*cmba=(const float*)d_in[11];
  const float* w0b=(const float*)d_in[12], *w1b=(const float*)d_in[13], *w2b=(const float*)d_in[14];
  const float* b0b=(const float*)d_in[15], *kb =(const float*)d_in[16];
  const float* cmWb=(const float*)d_in[17],*cmbb=(const float*)d_in[18];
  const float* Wda=(const float*)d_in[19], *bda=(const float*)d_in[20];
  const float* Wdb=(const float*)d_in[21], *bdb=(const float*)d_in[22];
  float* out = (float*)d_out;

  const int n4 = (NN*NC*9)/4;  // 1,440,000 float4s
  init_out_kernel<<<(n4+TPB-1)/TPB, TPB, 0, stream>>>((const float4*)nodes_rec, (float4*)out, n4);
  edge_kernel<<<NE/EPB, TPB, 0, stream>>>(
      nodes_snd, edge_ind, Y_edge, dist_feat,
      w0a,w1a,w2a,b0a,ka,cmWa,cmba,
      w0b,w1b,w2b,b0b,kb,cmWb,cmbb,
      Wda,bda,Wdb,bdb, out);
}

// Round 3
// 878.210 us; speedup vs baseline: 2.8167x; 2.8167x over previous
//
#include <hip/hip_runtime.h>

#define NE   256000
#define NN   20000
#define NC   32
#define NF   32

// ---- workspace layout (bytes) ---- total 1,264,000 B (~1.21 MB)
#define WS_CNT   0u          // NN i32 : per-receiver edge count
#define WS_OFF   80000u      // NN i32 : CSR offsets
#define WS_CUR   160000u     // NN i32 : scatter cursors
#define WS_ELIST 240000u     // NE i32 : edge ids grouped by receiver

// ---------------- compile-time real Clebsch-Gordan tables ----------------
namespace cg {

constexpr double cfact(int n){ double r=1.0; for(int i=2;i<=n;++i) r*=(double)i; return r; }
constexpr double cabsd(double x){ return x<0.0?-x:x; }
constexpr double csqrt(double x){
  if(x<=0.0) return 0.0;
  double g = x<1.0 ? 1.0 : x;
  for(int i=0;i<100;++i) g = 0.5*(g + x/g);
  return g;
}
constexpr double cw3j(int j1,int j2,int j3,int m1,int m2,int m3){
  if(m1+m2+m3!=0) return 0.0;
  int dj = j1-j2; int adj = dj<0?-dj:dj;
  if(j3<adj || j3>j1+j2) return 0.0;
  int t1=j2-m1-j3, t2=j1+m2-j3, t3=j1+j2-j3, t4=j1-m1, t5=j2+m2;
  int tmin = 0; if(t1>tmin)tmin=t1; if(t2>tmin)tmin=t2;
  int tmax = t3; if(t4<tmax)tmax=t4; if(t5<tmax)tmax=t5;
  double s=0.0;
  for(int t=tmin;t<=tmax;++t){
    double d = cfact(t)*cfact(t-t1)*cfact(t-t2)*cfact(t3-t)*cfact(t4-t)*cfact(t5-t);
    s += ((t&1)? -1.0:1.0)/d;
  }
  double delta = cfact(j1+j2-j3)*cfact(j1-j2+j3)*cfact(-j1+j2+j3)/cfact(j1+j2+j3+1);
  double norm = csqrt(delta*cfact(j1+m1)*cfact(j1-m1)*cfact(j2+m2)*cfact(j2-m2)*cfact(j3+m3)*cfact(j3-m3));
  int e = j1-j2-m3;
  double ph = (e%2!=0)? -1.0 : 1.0;
  return ph*norm*s;
}
struct KD { double re, im; };
struct UM { KD m[5][5]; };
constexpr UM u_real(int l){
  UM U{};
  U.m[l][l] = KD{1.0,0.0};
  double s2 = 0.70710678118654752440;
  for(int mm=1;mm<=l;++mm){
    double sg = (mm&1)? -1.0:1.0;
    U.m[l+mm][l+mm] = KD{sg*s2, 0.0};
    U.m[l+mm][l-mm] = KD{s2, 0.0};
    U.m[l-mm][l+mm] = KD{0.0, -sg*s2};
    U.m[l-mm][l-mm] = KD{0.0, s2};
  }
  return U;
}
struct T3 { double v[5][5][5]; };
constexpr T3 real_cg(int l1,int l2,int l3){
  KD T[5][5][5]{};
  UM U1=u_real(l1), U2=u_real(l2), U3=u_real(l3);
  for(int m1=-l1;m1<=l1;++m1)
  for(int m2=-l2;m2<=l2;++m2){
    int m3 = -(m1+m2);
    if(m3<-l3 || m3>l3) continue;
    double w = cw3j(l1,l2,l3,m1,m2,m3);
    if(w==0.0) continue;
    for(int a=0;a<2*l1+1;++a){
      KD u1 = U1.m[a][l1+m1];
      if(u1.re==0.0 && u1.im==0.0) continue;
      for(int b=0;b<2*l2+1;++b){
        KD u2 = U2.m[b][l2+m2];
        if(u2.re==0.0 && u2.im==0.0) continue;
        KD u12 = KD{u1.re*u2.re - u1.im*u2.im, u1.re*u2.im + u1.im*u2.re};
        for(int c=0;c<2*l3+1;++c){
          KD u3 = U3.m[c][l3+m3];
          if(u3.re==0.0 && u3.im==0.0) continue;
          KD u123 = KD{u12.re*u3.re - u12.im*u3.im, u12.re*u3.im + u12.im*u3.re};
          T[a][b][c].re += u123.re*w;
          T[a][b][c].im += u123.im*w;
        }
      }
    }
  }
  double mr=0.0, mi=0.0;
  for(int a=0;a<5;++a)for(int b=0;b<5;++b)for(int c=0;c<5;++c){
    if(cabsd(T[a][b][c].re)>mr) mr=cabsd(T[a][b][c].re);
    if(cabsd(T[a][b][c].im)>mi) mi=cabsd(T[a][b][c].im);
  }
  T3 R{};
  for(int a=0;a<5;++a)for(int b=0;b<5;++b)for(int c=0;c<5;++c)
    R.v[a][b][c] = (mr>=mi)? T[a][b][c].re : T[a][b][c].im;
  return R;
}
constexpr int MAXE = 320;
struct List { int n; int p[MAXE]; int a[MAXE]; int b[MAXE]; int c[MAXE]; float v[MAXE]; };
constexpr List build(){
  List L{};
  const int PMP[11][3]={{0,0,0},{1,1,0},{2,2,0},{0,1,1},{1,0,1},{1,2,1},{2,1,1},{0,2,2},{1,1,2},{2,0,2},{2,2,2}};
  const int LOFF[3]={0,1,4};
  const int NP[3]={3,4,4};
  for(int p=0;p<11;++p){
    int l1=PMP[p][0], l2=PMP[p][1], l3=PMP[p][2];
    T3 T = real_cg(l1,l2,l3);
    double fac = csqrt((2.0*l3+1.0)/(double)NP[l3]);
    for(int a=0;a<2*l1+1;++a)for(int b=0;b<2*l2+1;++b)for(int c=0;c<2*l3+1;++c){
      double v = T.v[a][b][c];
      if((v>1e-12 || v<-1e-12) && L.n < MAXE){
        L.p[L.n]=p; L.a[L.n]=LOFF[l1]+a; L.b[L.n]=LOFF[l2]+b; L.c[L.n]=LOFF[l3]+c;
        L.v[L.n]=(float)(v*fac);
        L.n++;
      }
    }
  }
  return L;
}
constexpr List CGL = build();
static_assert(CGL.n > 0 && CGL.n < MAXE, "CG table overflow/empty");
} // namespace cg

// pair_mix contraction: acc[c] += w[p]*v * x[a]*y[b]
template<int K>
__device__ __forceinline__ void cg_accum(float* acc, const float* w, const float* x, const float* y){
  if constexpr (K < cg::CGL.n){
    constexpr int   p  = cg::CGL.p[K];
    constexpr int   a  = cg::CGL.a[K];
    constexpr int   b  = cg::CGL.b[K];
    constexpr int   cc = cg::CGL.c[K];
    constexpr float v  = cg::CGL.v[K];
    acc[cc] = fmaf(w[p]*v, x[a]*y[b], acc[cc]);
    cg_accum<K+1>(acc, w, x, y);
  }
}

// dual selfmix contraction (branches a & b share the Y[a]*Y[b] product)
template<int K>
__device__ __forceinline__ void cg_accum2(float* za, float* zb, const float* wA, const float* wB, const float* Y){
  if constexpr (K < cg::CGL.n){
    constexpr int   p  = cg::CGL.p[K];
    constexpr int   a  = cg::CGL.a[K];
    constexpr int   b  = cg::CGL.b[K];
    constexpr int   cc = cg::CGL.c[K];
    constexpr float v  = cg::CGL.v[K];
    const float prod = Y[a]*Y[b];
    za[cc] = fmaf(wA[p]*v, prod, za[cc]);
    zb[cc] = fmaf(wB[p]*v, prod, zb[cc]);
    cg_accum2<K+1>(za, zb, wA, wB, Y);
  }
}

// ---------------- CSR build ----------------
__global__ __launch_bounds__(256) void hist_kernel(const int* __restrict__ edge_ind, int* __restrict__ cnt){
  int e = blockIdx.x*256 + threadIdx.x;
  if(e < NE) atomicAdd(&cnt[edge_ind[2*e+1]], 1);
}

__global__ __launch_bounds__(1024) void scan_kernel(const int* __restrict__ cnt, int* __restrict__ offs){
  __shared__ int ps[1024];
  const int t = threadIdx.x;
  const int b = t*20;
  int loc[20]; int s=0;
  #pragma unroll
  for(int i=0;i<20;++i){ int idx=b+i; int v = (idx<NN)? cnt[idx] : 0; loc[i]=v; s+=v; }
  ps[t]=s; __syncthreads();
  for(int d=1; d<1024; d<<=1){
    int v = (t>=d)? ps[t-d] : 0;
    __syncthreads();
    ps[t]+=v;
    __syncthreads();
  }
  int run = ps[t]-s;  // exclusive prefix
  #pragma unroll
  for(int i=0;i<20;++i){ int idx=b+i; if(idx<NN) offs[idx]=run; run+=loc[i]; }
}

__global__ __launch_bounds__(256) void scatter_kernel(const int* __restrict__ edge_ind,
                                                      const int* __restrict__ offs,
                                                      int* __restrict__ cur,
                                                      int* __restrict__ elist){
  int e = blockIdx.x*256 + threadIdx.x;
  if(e >= NE) return;
  int r = edge_ind[2*e+1];
  int p = offs[r] + atomicAdd(&cur[r], 1);
  elist[p] = e;
}

// ---------------- main: one wave per receiver node, no atomics ----------------
__global__ __launch_bounds__(256) void node_kernel(
  const float* __restrict__ nodes_rec, const float* __restrict__ nodes_snd,
  const int* __restrict__ edge_ind,    const float* __restrict__ Y_edge,
  const float* __restrict__ dist_feat,
  const float* __restrict__ w0a, const float* __restrict__ w1a, const float* __restrict__ w2a,
  const float* __restrict__ b0a, const float* __restrict__ ka,
  const float* __restrict__ cmWa, const float* __restrict__ cmba,
  const float* __restrict__ w0b, const float* __restrict__ w1b, const float* __restrict__ w2b,
  const float* __restrict__ b0b, const float* __restrict__ kb,
  const float* __restrict__ cmWb, const float* __restrict__ cmbb,
  const float* __restrict__ Wda, const float* __restrict__ bda,
  const float* __restrict__ Wdb, const float* __restrict__ bdb,
  const int* __restrict__ cnt, const int* __restrict__ offs,
  const int* __restrict__ elist,
  float* __restrict__ out)
{
  // packed bf16 weight pairs: [f][q][c], dword q packs cols (2q,2q+1) of channel c's
  // 14 cols [a0,a1,a2,b0..b10]. bank = c -> conflict-free; halves broadcast. 28 KB.
  __shared__ unsigned int sWp[NF][7][32];

  const int t    = threadIdx.x;
  const int lane = t & 63;
  const int wv   = t >> 6;       // wave in block = node sub-index
  const int c    = lane & 31;    // channel
  const int h    = lane >> 5;    // half: edge-slot group

  for(int i=t; i<NF*7*32; i+=256){
    int f = i/224; int r = i%224; int q = r>>5; int cc = r&31;
    int j0 = 2*q, j1 = 2*q+1;
    float v0 = (j0<3) ? Wda[f*96 + cc*3 + j0] : Wdb[f*352 + cc*11 + (j0-3)];
    float v1 = (j1<3) ? Wda[f*96 + cc*3 + j1] : Wdb[f*352 + cc*11 + (j1-3)];
    unsigned u0 = __float_as_uint(v0); u0 += 0x7fffu + ((u0>>16)&1u);  // RNE to bf16
    unsigned u1 = __float_as_uint(v1); u1 += 0x7fffu + ((u1>>16)&1u);
    sWp[f][q][cc] = (u0>>16) | (u1 & 0xffff0000u);
  }
  __syncthreads();

  const int node = blockIdx.x*4 + wv;
  const int deg  = cnt[node];
  const int off  = offs[node];

  // uniform selfmix weights (scalar loads)
  const float wsA[11] = {w0a[0],w0a[1],w0a[2], w1a[0],w1a[1],w1a[2],w1a[3], w2a[0],w2a[1],w2a[2],w2a[3]};
  const float wsB[11] = {w0b[0],w0b[1],w0b[2], w1b[0],w1b[1],w1b[2],w1b[3], w2b[0],w2b[1],w2b[2],w2b[3]};
  const float b0A=b0a[0], b0B=b0b[0];
  const float kA0=ka[0],kA1=ka[1],kA2=ka[2];
  const float kB0=kb[0],kB1=kb[1],kB2=kb[2];

  float bias[14];
  #pragma unroll
  for(int l=0;l<3;++l)  bias[l]   = bda[c*3+l];
  #pragma unroll
  for(int j=0;j<11;++j) bias[3+j] = bdb[c*11+j];
  const float cwa0=cmWa[c], cwa1=cmWa[NC+c], cwa2=cmWa[2*NC+c], cba=cmba[c];
  const float cwb0=cmWb[c], cwb1=cmWb[NC+c], cwb2=cmWb[2*NC+c], cbb=cmbb[c];

  float acc[9];
  #pragma unroll
  for(int m=0;m<9;++m) acc[m]=0.f;

  if(deg > 0){
    int ev = 0;
    for(int base=0; base<deg; base+=8){
      const int bi = base & 63;
      if(bi == 0){
        int li = off + (base & ~63) + lane;
        int mx = off + deg - 1;
        ev = elist[li < mx ? li : mx];
      }
      int eg[4];
      #pragma unroll
      for(int k=0;k<4;++k) eg[k] = __shfl(ev, bi + 4*h + k, 64);

      // ---- GEMM: wacc[k][0..2]=wa, [3..13]=wb for this lane's 4 edges ----
      float wacc[4][14];
      #pragma unroll
      for(int k=0;k<4;++k){
        #pragma unroll
        for(int j=0;j<14;++j) wacc[k][j] = bias[j];
      }
      #pragma unroll 2
      for(int fc=0; fc<NF; fc+=4){
        float4 dv[4];
        #pragma unroll
        for(int k=0;k<4;++k) dv[k] = *(const float4*)(dist_feat + (size_t)eg[k]*NF + fc);
        #pragma unroll
        for(int df=0; df<4; ++df){
          const int f = fc + df;
          float w[14];
          #pragma unroll
          for(int q=0;q<7;++q){
            unsigned d = sWp[f][q][c];
            w[2*q]   = __uint_as_float(d << 16);
            w[2*q+1] = __uint_as_float(d & 0xffff0000u);
          }
          #pragma unroll
          for(int k=0;k<4;++k){
            float dk = (df==0)?dv[k].x:(df==1)?dv[k].y:(df==2)?dv[k].z:dv[k].w;
            #pragma unroll
            for(int j=0;j<14;++j) wacc[k][j] = fmaf(dk, w[j], wacc[k][j]);
          }
        }
      }

      // ---- epilogue per edge slot (recompute selfmix from Y_edge) ----
      #pragma unroll
      for(int k=0;k<4;++k){
        const int idx = base + 4*h + k;
        if(idx < deg){
          const int e = eg[k];
          const int snd = edge_ind[2*e];
          const float* yp = Y_edge + (size_t)e*9;
          float Y[9];
          #pragma unroll
          for(int m=0;m<9;++m) Y[m]=yp[m];

          // selfmix a & b (shared Y products)
          float sa[9], sb[9];
          #pragma unroll
          for(int m=0;m<9;++m){ sa[m]=0.f; sb[m]=0.f; }
          cg_accum2<0>(sa, sb, wsA, wsB, Y);
          sa[0]+=b0A; sb[0]+=b0B;
          sa[0]+=kA0*Y[0];
          sa[1]+=kA1*Y[1]; sa[2]+=kA1*Y[2]; sa[3]+=kA1*Y[3];
          sa[4]+=kA2*Y[4]; sa[5]+=kA2*Y[5]; sa[6]+=kA2*Y[6]; sa[7]+=kA2*Y[7]; sa[8]+=kA2*Y[8];
          sb[0]+=kB0*Y[0];
          sb[1]+=kB1*Y[1]; sb[2]+=kB1*Y[2]; sb[3]+=kB1*Y[3];
          sb[4]+=kB2*Y[4]; sb[5]+=kB2*Y[5]; sb[6]+=kB2*Y[6]; sb[7]+=kB2*Y[7]; sb[8]+=kB2*Y[8];

          const float* xp = nodes_snd + ((size_t)snd*NC + c)*9;
          float x[9];
          #pragma unroll
          for(int m=0;m<9;++m) x[m]=xp[m];

          // channel mix -> ya, yb
          float ya[9], yb[9];
          ya[0]=fmaf(cwa0,sa[0],cba);
          ya[1]=cwa1*sa[1]; ya[2]=cwa1*sa[2]; ya[3]=cwa1*sa[3];
          ya[4]=cwa2*sa[4]; ya[5]=cwa2*sa[5]; ya[6]=cwa2*sa[6]; ya[7]=cwa2*sa[7]; ya[8]=cwa2*sa[8];
          yb[0]=fmaf(cwb0,sb[0],cbb);
          yb[1]=cwb1*sb[1]; yb[2]=cwb1*sb[2]; yb[3]=cwb1*sb[3];
          yb[4]=cwb2*sb[4]; yb[5]=cwb2*sb[5]; yb[6]=cwb2*sb[6]; yb[7]=cwb2*sb[7]; yb[8]=cwb2*sb[8];

          // branch a
          const float x0 = x[0];
          const float wa0 = wacc[k][0]*x0, wa1 = wacc[k][1]*x0, wa2 = wacc[k][2]*x0;
          acc[0]=fmaf(wa0,ya[0],acc[0]);
          acc[1]=fmaf(wa1,ya[1],acc[1]); acc[2]=fmaf(wa1,ya[2],acc[2]); acc[3]=fmaf(wa1,ya[3],acc[3]);
          acc[4]=fmaf(wa2,ya[4],acc[4]); acc[5]=fmaf(wa2,ya[5],acc[5]); acc[6]=fmaf(wa2,ya[6],acc[6]);
          acc[7]=fmaf(wa2,ya[7],acc[7]); acc[8]=fmaf(wa2,ya[8],acc[8]);

          // branch b: pair_mix
          cg_accum<0>(acc, &wacc[k][3], x, yb);
        }
      }
    }
  }

  // cross-half reduce, single write per output element (no atomics)
  #pragma unroll
  for(int m=0;m<9;++m) acc[m] += __shfl_down(acc[m], 32, 64);
  if(h == 0){
    float* op = out + ((size_t)node*NC + c)*9;
    const float* rp = nodes_rec + ((size_t)node*NC + c)*9;
    #pragma unroll
    for(int m=0;m<9;++m) op[m] = rp[m] + acc[m];
  }
}

// ---------------- launch ----------------
extern "C" void kernel_launch(void* const* d_in, const int* in_sizes, int n_in,
                              void* d_out, int out_size, void* d_ws, size_t ws_size,
                              hipStream_t stream) {
  const float* nodes_rec = (const float*)d_in[0];
  const float* nodes_snd = (const float*)d_in[1];
  const int*   edge_ind  = (const int*)  d_in[2];
  const float* Y_edge    = (const float*)d_in[3];
  const float* dist_feat = (const float*)d_in[4];
  const float* w0a=(const float*)d_in[5],  *w1a=(const float*)d_in[6],  *w2a=(const float*)d_in[7];
  const float* b0a=(const float*)d_in[8],  *ka =(const float*)d_in[9];
  const float* cmWa=(const float*)d_in[10],*cmba=(const float*)d_in[11];
  const float* w0b=(const float*)d_in[12], *w1b=(const float*)d_in[13], *w2b=(const float*)d_in[14];
  const float* b0b=(const float*)d_in[15], *kb =(const float*)d_in[16];
  const float* cmWb=(const float*)d_in[17],*cmbb=(const float*)d_in[18];
  const float* Wda=(const float*)d_in[19], *bda=(const float*)d_in[20];
  const float* Wdb=(const float*)d_in[21], *bdb=(const float*)d_in[22];
  float* out = (float*)d_out;

  char* ws = (char*)d_ws;
  int* cnt   = (int*)(ws + WS_CNT);
  int* offs  = (int*)(ws + WS_OFF);
  int* cur   = (int*)(ws + WS_CUR);
  int* elist = (int*)(ws + WS_ELIST);

  hipMemsetAsync(cnt, 0, NN*sizeof(int), stream);
  hipMemsetAsync(cur, 0, NN*sizeof(int), stream);

  hist_kernel   <<<NE/256, 256, 0, stream>>>(edge_ind, cnt);
  scan_kernel   <<<1, 1024, 0, stream>>>(cnt, offs);
  scatter_kernel<<<NE/256, 256, 0, stream>>>(edge_ind, offs, cur, elist);
  node_kernel   <<<NN/4, 256, 0, stream>>>(nodes_rec, nodes_snd, edge_ind, Y_edge, dist_feat,
                                           w0a,w1a,w2a,b0a,ka,cmWa,cmba,
                                           w0b,w1b,w2b,b0b,kb,cmWb,cmbb,
                                           Wda,bda,Wdb,bdb,
                                           cnt, offs, elist, out);
}

// Round 4
// 759.780 us; speedup vs baseline: 3.2557x; 1.1559x over previous
//
#include <hip/hip_runtime.h>

#define NE   256000
#define NN   20000
#define NC   32
#define NF   32

// ---- workspace layout (bytes) ---- total 1,264,000 B (~1.21 MB)
#define WS_CNT   0u          // NN i32 : per-receiver edge count
#define WS_CUR   80000u      // NN i32 : scatter cursors   (adjacent to cnt -> one memset)
#define WS_OFF   160000u     // NN i32 : CSR offsets
#define WS_ELIST 240000u     // NE i32 : edge ids grouped by receiver

// ---------------- compile-time real Clebsch-Gordan tables ----------------
namespace cg {

constexpr double cfact(int n){ double r=1.0; for(int i=2;i<=n;++i) r*=(double)i; return r; }
constexpr double cabsd(double x){ return x<0.0?-x:x; }
constexpr double csqrt(double x){
  if(x<=0.0) return 0.0;
  double g = x<1.0 ? 1.0 : x;
  for(int i=0;i<100;++i) g = 0.5*(g + x/g);
  return g;
}
constexpr double cw3j(int j1,int j2,int j3,int m1,int m2,int m3){
  if(m1+m2+m3!=0) return 0.0;
  int dj = j1-j2; int adj = dj<0?-dj:dj;
  if(j3<adj || j3>j1+j2) return 0.0;
  int t1=j2-m1-j3, t2=j1+m2-j3, t3=j1+j2-j3, t4=j1-m1, t5=j2+m2;
  int tmin = 0; if(t1>tmin)tmin=t1; if(t2>tmin)tmin=t2;
  int tmax = t3; if(t4<tmax)tmax=t4; if(t5<tmax)tmax=t5;
  double s=0.0;
  for(int t=tmin;t<=tmax;++t){
    double d = cfact(t)*cfact(t-t1)*cfact(t-t2)*cfact(t3-t)*cfact(t4-t)*cfact(t5-t);
    s += ((t&1)? -1.0:1.0)/d;
  }
  double delta = cfact(j1+j2-j3)*cfact(j1-j2+j3)*cfact(-j1+j2+j3)/cfact(j1+j2+j3+1);
  double norm = csqrt(delta*cfact(j1+m1)*cfact(j1-m1)*cfact(j2+m2)*cfact(j2-m2)*cfact(j3+m3)*cfact(j3-m3));
  int e = j1-j2-m3;
  double ph = (e%2!=0)? -1.0 : 1.0;
  return ph*norm*s;
}
struct KD { double re, im; };
struct UM { KD m[5][5]; };
constexpr UM u_real(int l){
  UM U{};
  U.m[l][l] = KD{1.0,0.0};
  double s2 = 0.70710678118654752440;
  for(int mm=1;mm<=l;++mm){
    double sg = (mm&1)? -1.0:1.0;
    U.m[l+mm][l+mm] = KD{sg*s2, 0.0};
    U.m[l+mm][l-mm] = KD{s2, 0.0};
    U.m[l-mm][l+mm] = KD{0.0, -sg*s2};
    U.m[l-mm][l-mm] = KD{0.0, s2};
  }
  return U;
}
struct T3 { double v[5][5][5]; };
constexpr T3 real_cg(int l1,int l2,int l3){
  KD T[5][5][5]{};
  UM U1=u_real(l1), U2=u_real(l2), U3=u_real(l3);
  for(int m1=-l1;m1<=l1;++m1)
  for(int m2=-l2;m2<=l2;++m2){
    int m3 = -(m1+m2);
    if(m3<-l3 || m3>l3) continue;
    double w = cw3j(l1,l2,l3,m1,m2,m3);
    if(w==0.0) continue;
    for(int a=0;a<2*l1+1;++a){
      KD u1 = U1.m[a][l1+m1];
      if(u1.re==0.0 && u1.im==0.0) continue;
      for(int b=0;b<2*l2+1;++b){
        KD u2 = U2.m[b][l2+m2];
        if(u2.re==0.0 && u2.im==0.0) continue;
        KD u12 = KD{u1.re*u2.re - u1.im*u2.im, u1.re*u2.im + u1.im*u2.re};
        for(int c=0;c<2*l3+1;++c){
          KD u3 = U3.m[c][l3+m3];
          if(u3.re==0.0 && u3.im==0.0) continue;
          KD u123 = KD{u12.re*u3.re - u12.im*u3.im, u12.re*u3.im + u12.im*u3.re};
          T[a][b][c].re += u123.re*w;
          T[a][b][c].im += u123.im*w;
        }
      }
    }
  }
  double mr=0.0, mi=0.0;
  for(int a=0;a<5;++a)for(int b=0;b<5;++b)for(int c=0;c<5;++c){
    if(cabsd(T[a][b][c].re)>mr) mr=cabsd(T[a][b][c].re);
    if(cabsd(T[a][b][c].im)>mi) mi=cabsd(T[a][b][c].im);
  }
  T3 R{};
  for(int a=0;a<5;++a)for(int b=0;b<5;++b)for(int c=0;c<5;++c)
    R.v[a][b][c] = (mr>=mi)? T[a][b][c].re : T[a][b][c].im;
  return R;
}
constexpr int MAXE = 320;
struct List { int n; int p[MAXE]; int a[MAXE]; int b[MAXE]; int c[MAXE]; float v[MAXE]; };
constexpr List build(){
  List L{};
  const int PMP[11][3]={{0,0,0},{1,1,0},{2,2,0},{0,1,1},{1,0,1},{1,2,1},{2,1,1},{0,2,2},{1,1,2},{2,0,2},{2,2,2}};
  const int LOFF[3]={0,1,4};
  const int NP[3]={3,4,4};
  for(int p=0;p<11;++p){
    int l1=PMP[p][0], l2=PMP[p][1], l3=PMP[p][2];
    T3 T = real_cg(l1,l2,l3);
    double fac = csqrt((2.0*l3+1.0)/(double)NP[l3]);
    for(int a=0;a<2*l1+1;++a)for(int b=0;b<2*l2+1;++b)for(int c=0;c<2*l3+1;++c){
      double v = T.v[a][b][c];
      if((v>1e-12 || v<-1e-12) && L.n < MAXE){
        L.p[L.n]=p; L.a[L.n]=LOFF[l1]+a; L.b[L.n]=LOFF[l2]+b; L.c[L.n]=LOFF[l3]+c;
        L.v[L.n]=(float)(v*fac);
        L.n++;
      }
    }
  }
  return L;
}
constexpr List CGL = build();
static_assert(CGL.n > 0 && CGL.n < MAXE, "CG table overflow/empty");
} // namespace cg

// pair_mix contraction: acc[c] += w[p]*v * x[a]*y[b]
template<int K>
__device__ __forceinline__ void cg_accum(float* acc, const float* w, const float* x, const float* y){
  if constexpr (K < cg::CGL.n){
    constexpr int   p  = cg::CGL.p[K];
    constexpr int   a  = cg::CGL.a[K];
    constexpr int   b  = cg::CGL.b[K];
    constexpr int   cc = cg::CGL.c[K];
    constexpr float v  = cg::CGL.v[K];
    acc[cc] = fmaf(w[p]*v, x[a]*y[b], acc[cc]);
    cg_accum<K+1>(acc, w, x, y);
  }
}

// dual selfmix contraction (branches a & b share the Y[a]*Y[b] product)
template<int K>
__device__ __forceinline__ void cg_accum2(float* za, float* zb, const float* wA, const float* wB, const float* Y){
  if constexpr (K < cg::CGL.n){
    constexpr int   p  = cg::CGL.p[K];
    constexpr int   a  = cg::CGL.a[K];
    constexpr int   b  = cg::CGL.b[K];
    constexpr int   cc = cg::CGL.c[K];
    constexpr float v  = cg::CGL.v[K];
    const float prod = Y[a]*Y[b];
    za[cc] = fmaf(wA[p]*v, prod, za[cc]);
    zb[cc] = fmaf(wB[p]*v, prod, zb[cc]);
    cg_accum2<K+1>(za, zb, wA, wB, Y);
  }
}

// ---------------- CSR build ----------------
__global__ __launch_bounds__(256) void hist_kernel(const int* __restrict__ edge_ind, int* __restrict__ cnt){
  int e = blockIdx.x*256 + threadIdx.x;
  if(e < NE) atomicAdd(&cnt[edge_ind[2*e+1]], 1);
}

__global__ __launch_bounds__(1024) void scan_kernel(const int* __restrict__ cnt, int* __restrict__ offs){
  __shared__ int ps[1024];
  const int t = threadIdx.x;
  const int b = t*20;
  int loc[20]; int s=0;
  #pragma unroll
  for(int i=0;i<20;++i){ int idx=b+i; int v = (idx<NN)? cnt[idx] : 0; loc[i]=v; s+=v; }
  ps[t]=s; __syncthreads();
  for(int d=1; d<1024; d<<=1){
    int v = (t>=d)? ps[t-d] : 0;
    __syncthreads();
    ps[t]+=v;
    __syncthreads();
  }
  int run = ps[t]-s;  // exclusive prefix
  #pragma unroll
  for(int i=0;i<20;++i){ int idx=b+i; if(idx<NN) offs[idx]=run; run+=loc[i]; }
}

__global__ __launch_bounds__(256) void scatter_kernel(const int* __restrict__ edge_ind,
                                                      const int* __restrict__ offs,
                                                      int* __restrict__ cur,
                                                      int* __restrict__ elist){
  int e = blockIdx.x*256 + threadIdx.x;
  if(e >= NE) return;
  int r = edge_ind[2*e+1];
  int p = offs[r] + atomicAdd(&cur[r], 1);
  elist[p] = e;
}

// ---------------- main: one wave per receiver node, no atomics ----------------
__global__ __launch_bounds__(256) void node_kernel(
  const float* __restrict__ nodes_rec, const float* __restrict__ nodes_snd,
  const int* __restrict__ edge_ind,    const float* __restrict__ Y_edge,
  const float* __restrict__ dist_feat,
  const float* __restrict__ w0a, const float* __restrict__ w1a, const float* __restrict__ w2a,
  const float* __restrict__ b0a, const float* __restrict__ ka,
  const float* __restrict__ cmWa, const float* __restrict__ cmba,
  const float* __restrict__ w0b, const float* __restrict__ w1b, const float* __restrict__ w2b,
  const float* __restrict__ b0b, const float* __restrict__ kb,
  const float* __restrict__ cmWb, const float* __restrict__ cmbb,
  const float* __restrict__ Wda, const float* __restrict__ bda,
  const float* __restrict__ Wdb, const float* __restrict__ bdb,
  const int* __restrict__ cnt, const int* __restrict__ offs,
  const int* __restrict__ elist,
  float* __restrict__ out)
{
  // packed bf16 weight pairs: [f][q][c]; bank = c -> conflict-free; halves broadcast. 28 KB.
  __shared__ unsigned int sWp[NF][7][32];
  // wave-private selfmix records: 64 edges x 20 dwords {sa[9], sb[9], e, snd}. 20 KB.
  __shared__ float sRec[4][64*20];

  const int t    = threadIdx.x;
  const int lane = t & 63;
  const int wv   = t >> 6;       // wave in block = node sub-index
  const int c    = lane & 31;    // channel
  const int h    = lane >> 5;    // half: edge-slot group

  for(int i=t; i<NF*7*32; i+=256){
    int f = i/224; int r = i%224; int q = r>>5; int cc = r&31;
    int j0 = 2*q, j1 = 2*q+1;
    float v0 = (j0<3) ? Wda[f*96 + cc*3 + j0] : Wdb[f*352 + cc*11 + (j0-3)];
    float v1 = (j1<3) ? Wda[f*96 + cc*3 + j1] : Wdb[f*352 + cc*11 + (j1-3)];
    unsigned u0 = __float_as_uint(v0); u0 += 0x7fffu + ((u0>>16)&1u);  // RNE to bf16
    unsigned u1 = __float_as_uint(v1); u1 += 0x7fffu + ((u1>>16)&1u);
    sWp[f][q][cc] = (u0>>16) | (u1 & 0xffff0000u);
  }
  __syncthreads();

  const int node = blockIdx.x*4 + wv;
  const int deg  = cnt[node];
  const int off  = offs[node];

  // uniform selfmix weights (scalar loads)
  const float wsA[11] = {w0a[0],w0a[1],w0a[2], w1a[0],w1a[1],w1a[2],w1a[3], w2a[0],w2a[1],w2a[2],w2a[3]};
  const float wsB[11] = {w0b[0],w0b[1],w0b[2], w1b[0],w1b[1],w1b[2],w1b[3], w2b[0],w2b[1],w2b[2],w2b[3]};
  const float b0A=b0a[0], b0B=b0b[0];
  const float kA0=ka[0],kA1=ka[1],kA2=ka[2];
  const float kB0=kb[0],kB1=kb[1],kB2=kb[2];

  float bias[14];
  #pragma unroll
  for(int l=0;l<3;++l)  bias[l]   = bda[c*3+l];
  #pragma unroll
  for(int j=0;j<11;++j) bias[3+j] = bdb[c*11+j];
  const float cwa0=cmWa[c], cwa1=cmWa[NC+c], cwa2=cmWa[2*NC+c], cba=cmba[c];
  const float cwb0=cmWb[c], cwb1=cmWb[NC+c], cwb2=cmWb[2*NC+c], cbb=cmbb[c];

  float acc[9];
  #pragma unroll
  for(int m=0;m<9;++m) acc[m]=0.f;

  for(int base64=0; base64<deg; base64+=64){
    const int nwin = (deg-base64 < 64) ? (deg-base64) : 64;

    // ---- phase 1: one lane per edge -> selfmix record in LDS ----
    __builtin_amdgcn_wave_barrier();
    if(lane < nwin){
      const int e   = elist[off + base64 + lane];
      const int snd = edge_ind[2*e];
      const float* yp = Y_edge + (size_t)e*9;
      float Y[9];
      #pragma unroll
      for(int m=0;m<9;++m) Y[m]=yp[m];

      float sa[9], sb[9];
      #pragma unroll
      for(int m=0;m<9;++m){ sa[m]=0.f; sb[m]=0.f; }
      cg_accum2<0>(sa, sb, wsA, wsB, Y);
      sa[0]+=b0A; sb[0]+=b0B;
      sa[0]+=kA0*Y[0];
      sa[1]+=kA1*Y[1]; sa[2]+=kA1*Y[2]; sa[3]+=kA1*Y[3];
      sa[4]+=kA2*Y[4]; sa[5]+=kA2*Y[5]; sa[6]+=kA2*Y[6]; sa[7]+=kA2*Y[7]; sa[8]+=kA2*Y[8];
      sb[0]+=kB0*Y[0];
      sb[1]+=kB1*Y[1]; sb[2]+=kB1*Y[2]; sb[3]+=kB1*Y[3];
      sb[4]+=kB2*Y[4]; sb[5]+=kB2*Y[5]; sb[6]+=kB2*Y[6]; sb[7]+=kB2*Y[7]; sb[8]+=kB2*Y[8];

      float* rp = &sRec[wv][lane*20];
      *(float4*)(rp+0)  = make_float4(sa[0],sa[1],sa[2],sa[3]);
      *(float4*)(rp+4)  = make_float4(sa[4],sa[5],sa[6],sa[7]);
      *(float4*)(rp+8)  = make_float4(sa[8],sb[0],sb[1],sb[2]);
      *(float4*)(rp+12) = make_float4(sb[3],sb[4],sb[5],sb[6]);
      *(float4*)(rp+16) = make_float4(sb[7],sb[8],__int_as_float(e),__int_as_float(snd));
    }
    __builtin_amdgcn_wave_barrier();

    // ---- phase 2: groups of 8 edges (4 per lane-half) ----
    for(int b8=0; b8<nwin; b8+=8){
      int e4[4], s4[4];
      const float* rp4[4];
      #pragma unroll
      for(int k=0;k<4;++k){
        int s = b8 + 4*h + k;
        int cs = (s < nwin) ? s : nwin-1;
        const float* rp = &sRec[wv][cs*20];
        rp4[k] = rp;
        e4[k] = __float_as_int(rp[18]);
        s4[k] = __float_as_int(rp[19]);
      }

      // ---- GEMM: wacc[k][0..2]=wa, [3..13]=wb ----
      float wacc[4][14];
      #pragma unroll
      for(int k=0;k<4;++k){
        #pragma unroll
        for(int j=0;j<14;++j) wacc[k][j] = bias[j];
      }
      #pragma unroll 2
      for(int fc=0; fc<NF; fc+=4){
        float4 dv[4];
        #pragma unroll
        for(int k=0;k<4;++k) dv[k] = *(const float4*)(dist_feat + (size_t)e4[k]*NF + fc);
        #pragma unroll
        for(int df=0; df<4; ++df){
          const int f = fc + df;
          float w[14];
          #pragma unroll
          for(int q=0;q<7;++q){
            unsigned d = sWp[f][q][c];
            w[2*q]   = __uint_as_float(d << 16);
            w[2*q+1] = __uint_as_float(d & 0xffff0000u);
          }
          #pragma unroll
          for(int k=0;k<4;++k){
            float dk = (df==0)?dv[k].x:(df==1)?dv[k].y:(df==2)?dv[k].z:dv[k].w;
            #pragma unroll
            for(int j=0;j<14;++j) wacc[k][j] = fmaf(dk, w[j], wacc[k][j]);
          }
        }
      }

      // ---- epilogue per edge slot ----
      #pragma unroll
      for(int k=0;k<4;++k){
        const int s = b8 + 4*h + k;
        if(s < nwin){
          const float* rp = rp4[k];
          float4 A0 = *(const float4*)(rp+0);
          float4 A1 = *(const float4*)(rp+4);
          float4 A2 = *(const float4*)(rp+8);
          float4 A3 = *(const float4*)(rp+12);
          float4 A4 = *(const float4*)(rp+16);
          // sa = {A0.xyzw, A1.xyzw, A2.x}; sb = {A2.yzw, A3.xyzw, A4.xy}
          const float* xp = nodes_snd + ((size_t)s4[k]*NC + c)*9;
          float x[9];
          #pragma unroll
          for(int m=0;m<9;++m) x[m]=xp[m];

          // channel mix -> ya, yb
          float ya[9], yb[9];
          ya[0]=fmaf(cwa0,A0.x,cba);
          ya[1]=cwa1*A0.y; ya[2]=cwa1*A0.z; ya[3]=cwa1*A0.w;
          ya[4]=cwa2*A1.x; ya[5]=cwa2*A1.y; ya[6]=cwa2*A1.z; ya[7]=cwa2*A1.w; ya[8]=cwa2*A2.x;
          yb[0]=fmaf(cwb0,A2.y,cbb);
          yb[1]=cwb1*A2.z; yb[2]=cwb1*A2.w; yb[3]=cwb1*A3.x;
          yb[4]=cwb2*A3.y; yb[5]=cwb2*A3.z; yb[6]=cwb2*A3.w; yb[7]=cwb2*A4.x; yb[8]=cwb2*A4.y;

          // branch a
          const float x0 = x[0];
          const float wa0 = wacc[k][0]*x0, wa1 = wacc[k][1]*x0, wa2 = wacc[k][2]*x0;
          acc[0]=fmaf(wa0,ya[0],acc[0]);
          acc[1]=fmaf(wa1,ya[1],acc[1]); acc[2]=fmaf(wa1,ya[2],acc[2]); acc[3]=fmaf(wa1,ya[3],acc[3]);
          acc[4]=fmaf(wa2,ya[4],acc[4]); acc[5]=fmaf(wa2,ya[5],acc[5]); acc[6]=fmaf(wa2,ya[6],acc[6]);
          acc[7]=fmaf(wa2,ya[7],acc[7]); acc[8]=fmaf(wa2,ya[8],acc[8]);

          // branch b: pair_mix
          cg_accum<0>(acc, &wacc[k][3], x, yb);
        }
      }
    }
  }

  // cross-half reduce, single write per output element (no atomics)
  #pragma unroll
  for(int m=0;m<9;++m) acc[m] += __shfl_down(acc[m], 32, 64);
  if(h == 0){
    float* op = out + ((size_t)node*NC + c)*9;
    const float* rp = nodes_rec + ((size_t)node*NC + c)*9;
    #pragma unroll
    for(int m=0;m<9;++m) op[m] = rp[m] + acc[m];
  }
}

// ---------------- launch ----------------
extern "C" void kernel_launch(void* const* d_in, const int* in_sizes, int n_in,
                              void* d_out, int out_size, void* d_ws, size_t ws_size,
                              hipStream_t stream) {
  const float* nodes_rec = (const float*)d_in[0];
  const float* nodes_snd = (const float*)d_in[1];
  const int*   edge_ind  = (const int*)  d_in[2];
  const float* Y_edge    = (const float*)d_in[3];
  const float* dist_feat = (const float*)d_in[4];
  const float* w0a=(const float*)d_in[5],  *w1a=(const float*)d_in[6],  *w2a=(const float*)d_in[7];
  const float* b0a=(const float*)d_in[8],  *ka =(const float*)d_in[9];
  const float* cmWa=(const float*)d_in[10],*cmba=(const float*)d_in[11];
  const float* w0b=(const float*)d_in[12], *w1b=(const float*)d_in[13], *w2b=(const float*)d_in[14];
  const float* b0b=(const float*)d_in[15], *kb =(const float*)d_in[16];
  const float* cmWb=(const float*)d_in[17],*cmbb=(const float*)d_in[18];
  const float* Wda=(const float*)d_in[19], *bda=(const float*)d_in[20];
  const float* Wdb=(const float*)d_in[21], *bdb=(const float*)d_in[22];
  float* out = (float*)d_out;

  char* ws = (char*)d_ws;
  int* cnt   = (int*)(ws + WS_CNT);
  int* cur   = (int*)(ws + WS_CUR);
  int* offs  = (int*)(ws + WS_OFF);
  int* elist = (int*)(ws + WS_ELIST);

  hipMemsetAsync(cnt, 0, 2*NN*sizeof(int), stream);   // cnt + cur in one shot

  hist_kernel   <<<NE/256, 256, 0, stream>>>(edge_ind, cnt);
  scan_kernel   <<<1, 1024, 0, stream>>>(cnt, offs);
  scatter_kernel<<<NE/256, 256, 0, stream>>>(edge_ind, offs, cur, elist);
  node_kernel   <<<NN/4, 256, 0, stream>>>(nodes_rec, nodes_snd, edge_ind, Y_edge, dist_feat,
                                           w0a,w1a,w2a,b0a,ka,cmWa,cmba,
                                           w0b,w1b,w2b,b0b,kb,cmWb,cmbb,
                                           Wda,bda,Wdb,bdb,
                                           cnt, offs, elist, out);
}

// Round 5
// 563.291 us; speedup vs baseline: 4.3914x; 1.3488x over previous
//
#include <hip/hip_runtime.h>

#define NE   256000
#define NN   20000
#define NC   32
#define NF   32

// ---- workspace layout (bytes) ----
// small path (always available): CSR only, 1,264,000 B
#define WS_CNT   0u          // NN i32
#define WS_CUR   80000u      // NN i32 (adjacent to cnt -> one memset)
#define WS_OFF   160000u     // NN i32
#define WS_ELIST 240000u     // NE i32
// big path extras:
#define WS_SSM   1264000u    // NE*20 f32 selfmix records (20,480,000 B)
#define WS_MSG   21744000u   // NE*32*5 u32 packed bf16 messages (163,840,000 B)
#define WS_NEED_BIG 185584000ull

// ---------------- compile-time real Clebsch-Gordan tables ----------------
namespace cg {

constexpr double cfact(int n){ double r=1.0; for(int i=2;i<=n;++i) r*=(double)i; return r; }
constexpr double cabsd(double x){ return x<0.0?-x:x; }
constexpr double csqrt(double x){
  if(x<=0.0) return 0.0;
  double g = x<1.0 ? 1.0 : x;
  for(int i=0;i<100;++i) g = 0.5*(g + x/g);
  return g;
}
constexpr double cw3j(int j1,int j2,int j3,int m1,int m2,int m3){
  if(m1+m2+m3!=0) return 0.0;
  int dj = j1-j2; int adj = dj<0?-dj:dj;
  if(j3<adj || j3>j1+j2) return 0.0;
  int t1=j2-m1-j3, t2=j1+m2-j3, t3=j1+j2-j3, t4=j1-m1, t5=j2+m2;
  int tmin = 0; if(t1>tmin)tmin=t1; if(t2>tmin)tmin=t2;
  int tmax = t3; if(t4<tmax)tmax=t4; if(t5<tmax)tmax=t5;
  double s=0.0;
  for(int t=tmin;t<=tmax;++t){
    double d = cfact(t)*cfact(t-t1)*cfact(t-t2)*cfact(t3-t)*cfact(t4-t)*cfact(t5-t);
    s += ((t&1)? -1.0:1.0)/d;
  }
  double delta = cfact(j1+j2-j3)*cfact(j1-j2+j3)*cfact(-j1+j2+j3)/cfact(j1+j2+j3+1);
  double norm = csqrt(delta*cfact(j1+m1)*cfact(j1-m1)*cfact(j2+m2)*cfact(j2-m2)*cfact(j3+m3)*cfact(j3-m3));
  int e = j1-j2-m3;
  double ph = (e%2!=0)? -1.0 : 1.0;
  return ph*norm*s;
}
struct KD { double re, im; };
struct UM { KD m[5][5]; };
constexpr UM u_real(int l){
  UM U{};
  U.m[l][l] = KD{1.0,0.0};
  double s2 = 0.70710678118654752440;
  for(int mm=1;mm<=l;++mm){
    double sg = (mm&1)? -1.0:1.0;
    U.m[l+mm][l+mm] = KD{sg*s2, 0.0};
    U.m[l+mm][l-mm] = KD{s2, 0.0};
    U.m[l-mm][l+mm] = KD{0.0, -sg*s2};
    U.m[l-mm][l-mm] = KD{0.0, s2};
  }
  return U;
}
struct T3 { double v[5][5][5]; };
constexpr T3 real_cg(int l1,int l2,int l3){
  KD T[5][5][5]{};
  UM U1=u_real(l1), U2=u_real(l2), U3=u_real(l3);
  for(int m1=-l1;m1<=l1;++m1)
  for(int m2=-l2;m2<=l2;++m2){
    int m3 = -(m1+m2);
    if(m3<-l3 || m3>l3) continue;
    double w = cw3j(l1,l2,l3,m1,m2,m3);
    if(w==0.0) continue;
    for(int a=0;a<2*l1+1;++a){
      KD u1 = U1.m[a][l1+m1];
      if(u1.re==0.0 && u1.im==0.0) continue;
      for(int b=0;b<2*l2+1;++b){
        KD u2 = U2.m[b][l2+m2];
        if(u2.re==0.0 && u2.im==0.0) continue;
        KD u12 = KD{u1.re*u2.re - u1.im*u2.im, u1.re*u2.im + u1.im*u2.re};
        for(int c=0;c<2*l3+1;++c){
          KD u3 = U3.m[c][l3+m3];
          if(u3.re==0.0 && u3.im==0.0) continue;
          KD u123 = KD{u12.re*u3.re - u12.im*u3.im, u12.re*u3.im + u12.im*u3.re};
          T[a][b][c].re += u123.re*w;
          T[a][b][c].im += u123.im*w;
        }
      }
    }
  }
  double mr=0.0, mi=0.0;
  for(int a=0;a<5;++a)for(int b=0;b<5;++b)for(int c=0;c<5;++c){
    if(cabsd(T[a][b][c].re)>mr) mr=cabsd(T[a][b][c].re);
    if(cabsd(T[a][b][c].im)>mi) mi=cabsd(T[a][b][c].im);
  }
  T3 R{};
  for(int a=0;a<5;++a)for(int b=0;b<5;++b)for(int c=0;c<5;++c)
    R.v[a][b][c] = (mr>=mi)? T[a][b][c].re : T[a][b][c].im;
  return R;
}
constexpr int MAXE = 320;
struct List { int n; int p[MAXE]; int a[MAXE]; int b[MAXE]; int c[MAXE]; float v[MAXE]; };
constexpr List build(){
  List L{};
  const int PMP[11][3]={{0,0,0},{1,1,0},{2,2,0},{0,1,1},{1,0,1},{1,2,1},{2,1,1},{0,2,2},{1,1,2},{2,0,2},{2,2,2}};
  const int LOFF[3]={0,1,4};
  const int NP[3]={3,4,4};
  for(int p=0;p<11;++p){
    int l1=PMP[p][0], l2=PMP[p][1], l3=PMP[p][2];
    T3 T = real_cg(l1,l2,l3);
    double fac = csqrt((2.0*l3+1.0)/(double)NP[l3]);
    for(int a=0;a<2*l1+1;++a)for(int b=0;b<2*l2+1;++b)for(int c=0;c<2*l3+1;++c){
      double v = T.v[a][b][c];
      if((v>1e-12 || v<-1e-12) && L.n < MAXE){
        L.p[L.n]=p; L.a[L.n]=LOFF[l1]+a; L.b[L.n]=LOFF[l2]+b; L.c[L.n]=LOFF[l3]+c;
        L.v[L.n]=(float)(v*fac);
        L.n++;
      }
    }
  }
  return L;
}
constexpr List CGL = build();
static_assert(CGL.n > 0 && CGL.n < MAXE, "CG table overflow/empty");
} // namespace cg

// pair_mix contraction: acc[c] += w[p]*v * x[a]*y[b]
template<int K>
__device__ __forceinline__ void cg_accum(float* acc, const float* w, const float* x, const float* y){
  if constexpr (K < cg::CGL.n){
    constexpr int   p  = cg::CGL.p[K];
    constexpr int   a  = cg::CGL.a[K];
    constexpr int   b  = cg::CGL.b[K];
    constexpr int   cc = cg::CGL.c[K];
    constexpr float v  = cg::CGL.v[K];
    acc[cc] = fmaf(w[p]*v, x[a]*y[b], acc[cc]);
    cg_accum<K+1>(acc, w, x, y);
  }
}

// dual selfmix contraction (branches a & b share the Y[a]*Y[b] product)
template<int K>
__device__ __forceinline__ void cg_accum2(float* za, float* zb, const float* wA, const float* wB, const float* Y){
  if constexpr (K < cg::CGL.n){
    constexpr int   p  = cg::CGL.p[K];
    constexpr int   a  = cg::CGL.a[K];
    constexpr int   b  = cg::CGL.b[K];
    constexpr int   cc = cg::CGL.c[K];
    constexpr float v  = cg::CGL.v[K];
    const float prod = Y[a]*Y[b];
    za[cc] = fmaf(wA[p]*v, prod, za[cc]);
    zb[cc] = fmaf(wB[p]*v, prod, zb[cc]);
    cg_accum2<K+1>(za, zb, wA, wB, Y);
  }
}

__device__ __forceinline__ unsigned f2bf_rne(float x){
  unsigned u = __float_as_uint(x);
  u += 0x7fffu + ((u>>16)&1u);
  return u>>16;
}

// ---------------- CSR build ----------------
__global__ __launch_bounds__(256) void hist_kernel(const int* __restrict__ edge_ind, int* __restrict__ cnt){
  int e = blockIdx.x*256 + threadIdx.x;
  if(e < NE) atomicAdd(&cnt[edge_ind[2*e+1]], 1);
}

__global__ __launch_bounds__(1024) void scan_kernel(const int* __restrict__ cnt, int* __restrict__ offs){
  __shared__ int ps[1024];
  const int t = threadIdx.x;
  const int b = t*20;
  int loc[20]; int s=0;
  #pragma unroll
  for(int i=0;i<20;++i){ int idx=b+i; int v = (idx<NN)? cnt[idx] : 0; loc[i]=v; s+=v; }
  ps[t]=s; __syncthreads();
  for(int d=1; d<1024; d<<=1){
    int v = (t>=d)? ps[t-d] : 0;
    __syncthreads();
    ps[t]+=v;
    __syncthreads();
  }
  int run = ps[t]-s;  // exclusive prefix
  #pragma unroll
  for(int i=0;i<20;++i){ int idx=b+i; if(idx<NN) offs[idx]=run; run+=loc[i]; }
}

__global__ __launch_bounds__(256) void scatter_kernel(const int* __restrict__ edge_ind,
                                                      const int* __restrict__ offs,
                                                      int* __restrict__ cur,
                                                      int* __restrict__ elist){
  int e = blockIdx.x*256 + threadIdx.x;
  if(e >= NE) return;
  int r = edge_ind[2*e+1];
  int p = offs[r] + atomicAdd(&cur[r], 1);
  elist[p] = e;
}

// ---------------- per-edge selfmix precompute (big path) ----------------
__global__ __launch_bounds__(256) void selfmix_kernel(
  const float* __restrict__ Y_edge,
  const float* __restrict__ w0a, const float* __restrict__ w1a, const float* __restrict__ w2a,
  const float* __restrict__ b0a, const float* __restrict__ ka,
  const float* __restrict__ w0b, const float* __restrict__ w1b, const float* __restrict__ w2b,
  const float* __restrict__ b0b, const float* __restrict__ kb,
  float* __restrict__ ssm)
{
  int e = blockIdx.x*256 + threadIdx.x;
  if(e >= NE) return;
  const float* yp = Y_edge + (size_t)e*9;
  float Y[9];
  #pragma unroll
  for(int m=0;m<9;++m) Y[m]=yp[m];

  const float wsA[11] = {w0a[0],w0a[1],w0a[2], w1a[0],w1a[1],w1a[2],w1a[3], w2a[0],w2a[1],w2a[2],w2a[3]};
  const float wsB[11] = {w0b[0],w0b[1],w0b[2], w1b[0],w1b[1],w1b[2],w1b[3], w2b[0],w2b[1],w2b[2],w2b[3]};

  float za[9], zb[9];
  #pragma unroll
  for(int m=0;m<9;++m){ za[m]=0.f; zb[m]=0.f; }
  cg_accum2<0>(za, zb, wsA, wsB, Y);
  za[0]+=b0a[0]; zb[0]+=b0b[0];
  {
    float k0=ka[0],k1=ka[1],k2=ka[2];
    za[0]+=k0*Y[0];
    za[1]+=k1*Y[1]; za[2]+=k1*Y[2]; za[3]+=k1*Y[3];
    za[4]+=k2*Y[4]; za[5]+=k2*Y[5]; za[6]+=k2*Y[6]; za[7]+=k2*Y[7]; za[8]+=k2*Y[8];
  }
  {
    float k0=kb[0],k1=kb[1],k2=kb[2];
    zb[0]+=k0*Y[0];
    zb[1]+=k1*Y[1]; zb[2]+=k1*Y[2]; zb[3]+=k1*Y[3];
    zb[4]+=k2*Y[4]; zb[5]+=k2*Y[5]; zb[6]+=k2*Y[6]; zb[7]+=k2*Y[7]; zb[8]+=k2*Y[8];
  }
  float4* o = (float4*)(ssm + (size_t)e*20);
  o[0] = make_float4(za[0],za[1],za[2],za[3]);
  o[1] = make_float4(za[4],za[5],za[6],za[7]);
  o[2] = make_float4(za[8],zb[0],zb[1],zb[2]);
  o[3] = make_float4(zb[3],zb[4],zb[5],zb[6]);
  o[4] = make_float4(zb[7],zb[8],0.f,0.f);
}

// ---------------- big path A: edge-parallel message kernel ----------------
__global__ __launch_bounds__(256,3) void edge_msg_kernel(
  const float* __restrict__ nodes_snd,
  const int* __restrict__ edge_ind,
  const float* __restrict__ dist_feat,
  const float* __restrict__ cmWa, const float* __restrict__ cmba,
  const float* __restrict__ cmWb, const float* __restrict__ cmbb,
  const float* __restrict__ Wda, const float* __restrict__ bda,
  const float* __restrict__ Wdb, const float* __restrict__ bdb,
  const float* __restrict__ ssm,
  unsigned int* __restrict__ msg)
{
  // packed bf16 weight pairs: [f][q][c]; bank = c -> conflict-free broadcast across q-groups. 28 KB.
  __shared__ unsigned int sWp[NF][7][32];

  const int t  = threadIdx.x;
  const int c  = t & 31;
  const int g2 = t >> 5;          // 0..7 -> owns edges eb+2*g2, eb+2*g2+1
  const int eb = blockIdx.x * 16;

  for(int i=t; i<NF*7*32; i+=256){
    int f = i/224; int r = i%224; int q = r>>5; int cc = r&31;
    int j0 = 2*q, j1 = 2*q+1;
    float v0 = (j0<3) ? Wda[f*96 + cc*3 + j0] : Wdb[f*352 + cc*11 + (j0-3)];
    float v1 = (j1<3) ? Wda[f*96 + cc*3 + j1] : Wdb[f*352 + cc*11 + (j1-3)];
    sWp[f][q][cc] = f2bf_rne(v0) | (f2bf_rne(v1) << 16);
  }
  __syncthreads();

  const int e0 = eb + 2*g2;
  const int e1 = e0 + 1;

  float bias[14];
  #pragma unroll
  for(int l=0;l<3;++l)  bias[l]   = bda[c*3+l];
  #pragma unroll
  for(int j=0;j<11;++j) bias[3+j] = bdb[c*11+j];
  const float cwa0=cmWa[c], cwa1=cmWa[NC+c], cwa2=cmWa[2*NC+c], cba=cmba[c];
  const float cwb0=cmWb[c], cwb1=cmWb[NC+c], cwb2=cmWb[2*NC+c], cbb=cmbb[c];

  // ---- GEMM: wacc[k][0..2]=wa, [3..13]=wb ----
  float wacc[2][14];
  #pragma unroll
  for(int k=0;k<2;++k){
    #pragma unroll
    for(int j=0;j<14;++j) wacc[k][j] = bias[j];
  }
  #pragma unroll 2
  for(int fc=0; fc<NF; fc+=4){
    float4 dv0 = *(const float4*)(dist_feat + (size_t)e0*NF + fc);
    float4 dv1 = *(const float4*)(dist_feat + (size_t)e1*NF + fc);
    #pragma unroll
    for(int df=0; df<4; ++df){
      const int f = fc + df;
      float w[14];
      #pragma unroll
      for(int q=0;q<7;++q){
        unsigned d = sWp[f][q][c];
        w[2*q]   = __uint_as_float(d << 16);
        w[2*q+1] = __uint_as_float(d & 0xffff0000u);
      }
      float d0 = (df==0)?dv0.x:(df==1)?dv0.y:(df==2)?dv0.z:dv0.w;
      float d1 = (df==0)?dv1.x:(df==1)?dv1.y:(df==2)?dv1.z:dv1.w;
      #pragma unroll
      for(int j=0;j<14;++j){
        wacc[0][j] = fmaf(d0, w[j], wacc[0][j]);
        wacc[1][j] = fmaf(d1, w[j], wacc[1][j]);
      }
    }
  }

  // ---- epilogue per edge slot: compute message, store bf16-packed ----
  #pragma unroll
  for(int k=0;k<2;++k){
    const int e = e0 + k;
    const int snd = edge_ind[2*e];
    const float* rp = ssm + (size_t)e*20;
    float4 A0 = *(const float4*)(rp+0);
    float4 A1 = *(const float4*)(rp+4);
    float4 A2 = *(const float4*)(rp+8);
    float4 A3 = *(const float4*)(rp+12);
    float4 A4 = *(const float4*)(rp+16);
    // sa = {A0.xyzw, A1.xyzw, A2.x}; sb = {A2.yzw, A3.xyzw, A4.xy}

    const float* xp = nodes_snd + ((size_t)snd*NC + c)*9;
    float x[9];
    #pragma unroll
    for(int m=0;m<9;++m) x[m]=xp[m];

    float ya[9], yb[9];
    ya[0]=fmaf(cwa0,A0.x,cba);
    ya[1]=cwa1*A0.y; ya[2]=cwa1*A0.z; ya[3]=cwa1*A0.w;
    ya[4]=cwa2*A1.x; ya[5]=cwa2*A1.y; ya[6]=cwa2*A1.z; ya[7]=cwa2*A1.w; ya[8]=cwa2*A2.x;
    yb[0]=fmaf(cwb0,A2.y,cbb);
    yb[1]=cwb1*A2.z; yb[2]=cwb1*A2.w; yb[3]=cwb1*A3.x;
    yb[4]=cwb2*A3.y; yb[5]=cwb2*A3.z; yb[6]=cwb2*A3.w; yb[7]=cwb2*A4.x; yb[8]=cwb2*A4.y;

    float mm[9];
    const float x0 = x[0];
    const float wa0 = wacc[k][0]*x0, wa1 = wacc[k][1]*x0, wa2 = wacc[k][2]*x0;
    mm[0]=wa0*ya[0];
    mm[1]=wa1*ya[1]; mm[2]=wa1*ya[2]; mm[3]=wa1*ya[3];
    mm[4]=wa2*ya[4]; mm[5]=wa2*ya[5]; mm[6]=wa2*ya[6]; mm[7]=wa2*ya[7]; mm[8]=wa2*ya[8];
    cg_accum<0>(mm, &wacc[k][3], x, yb);

    unsigned int* mp = msg + ((size_t)e*NC + c)*5;
    mp[0] = f2bf_rne(mm[0]) | (f2bf_rne(mm[1])<<16);
    mp[1] = f2bf_rne(mm[2]) | (f2bf_rne(mm[3])<<16);
    mp[2] = f2bf_rne(mm[4]) | (f2bf_rne(mm[5])<<16);
    mp[3] = f2bf_rne(mm[6]) | (f2bf_rne(mm[7])<<16);
    mp[4] = f2bf_rne(mm[8]);
  }
}

// ---------------- big path B: CSR gather (no atomics) ----------------
__global__ __launch_bounds__(256) void gather_kernel(
  const float* __restrict__ nodes_rec,
  const int* __restrict__ cnt, const int* __restrict__ offs,
  const int* __restrict__ elist,
  const unsigned int* __restrict__ msg,
  float* __restrict__ out)
{
  const int t    = threadIdx.x;
  const int lane = t & 63;
  const int wv   = t >> 6;
  const int c    = lane & 31;
  const int h    = lane >> 5;

  const int node = blockIdx.x*4 + wv;
  const int deg  = cnt[node];
  const int off  = offs[node];

  float acc[9];
  #pragma unroll
  for(int m=0;m<9;++m) acc[m]=0.f;

  for(int i=h; i<deg; i+=2){
    const int e = elist[off+i];
    const unsigned int* mp = msg + ((size_t)e*NC + c)*5;
    unsigned d0=mp[0], d1=mp[1], d2=mp[2], d3=mp[3], d4=mp[4];
    acc[0] += __uint_as_float(d0<<16);
    acc[1] += __uint_as_float(d0&0xffff0000u);
    acc[2] += __uint_as_float(d1<<16);
    acc[3] += __uint_as_float(d1&0xffff0000u);
    acc[4] += __uint_as_float(d2<<16);
    acc[5] += __uint_as_float(d2&0xffff0000u);
    acc[6] += __uint_as_float(d3<<16);
    acc[7] += __uint_as_float(d3&0xffff0000u);
    acc[8] += __uint_as_float(d4<<16);
  }

  #pragma unroll
  for(int m=0;m<9;++m) acc[m] += __shfl_down(acc[m], 32, 64);
  if(h == 0){
    float* op = out + ((size_t)node*NC + c)*9;
    const float* rp = nodes_rec + ((size_t)node*NC + c)*9;
    #pragma unroll
    for(int m=0;m<9;++m) op[m] = rp[m] + acc[m];
  }
}

// ---------------- fallback: round-4 fused node kernel (known good) ----------------
__global__ __launch_bounds__(256) void node_kernel(
  const float* __restrict__ nodes_rec, const float* __restrict__ nodes_snd,
  const int* __restrict__ edge_ind,    const float* __restrict__ Y_edge,
  const float* __restrict__ dist_feat,
  const float* __restrict__ w0a, const float* __restrict__ w1a, const float* __restrict__ w2a,
  const float* __restrict__ b0a, const float* __restrict__ ka,
  const float* __restrict__ cmWa, const float* __restrict__ cmba,
  const float* __restrict__ w0b, const float* __restrict__ w1b, const float* __restrict__ w2b,
  const float* __restrict__ b0b, const float* __restrict__ kb,
  const float* __restrict__ cmWb, const float* __restrict__ cmbb,
  const float* __restrict__ Wda, const float* __restrict__ bda,
  const float* __restrict__ Wdb, const float* __restrict__ bdb,
  const int* __restrict__ cnt, const int* __restrict__ offs,
  const int* __restrict__ elist,
  float* __restrict__ out)
{
  __shared__ unsigned int sWp[NF][7][32];
  __shared__ float sRec[4][64*20];

  const int t    = threadIdx.x;
  const int lane = t & 63;
  const int wv   = t >> 6;
  const int c    = lane & 31;
  const int h    = lane >> 5;

  for(int i=t; i<NF*7*32; i+=256){
    int f = i/224; int r = i%224; int q = r>>5; int cc = r&31;
    int j0 = 2*q, j1 = 2*q+1;
    float v0 = (j0<3) ? Wda[f*96 + cc*3 + j0] : Wdb[f*352 + cc*11 + (j0-3)];
    float v1 = (j1<3) ? Wda[f*96 + cc*3 + j1] : Wdb[f*352 + cc*11 + (j1-3)];
    sWp[f][q][cc] = f2bf_rne(v0) | (f2bf_rne(v1)<<16);
  }
  __syncthreads();

  const int node = blockIdx.x*4 + wv;
  const int deg  = cnt[node];
  const int off  = offs[node];

  const float wsA[11] = {w0a[0],w0a[1],w0a[2], w1a[0],w1a[1],w1a[2],w1a[3], w2a[0],w2a[1],w2a[2],w2a[3]};
  const float wsB[11] = {w0b[0],w0b[1],w0b[2], w1b[0],w1b[1],w1b[2],w1b[3], w2b[0],w2b[1],w2b[2],w2b[3]};
  const float b0A=b0a[0], b0B=b0b[0];
  const float kA0=ka[0],kA1=ka[1],kA2=ka[2];
  const float kB0=kb[0],kB1=kb[1],kB2=kb[2];

  float bias[14];
  #pragma unroll
  for(int l=0;l<3;++l)  bias[l]   = bda[c*3+l];
  #pragma unroll
  for(int j=0;j<11;++j) bias[3+j] = bdb[c*11+j];
  const float cwa0=cmWa[c], cwa1=cmWa[NC+c], cwa2=cmWa[2*NC+c], cba=cmba[c];
  const float cwb0=cmWb[c], cwb1=cmWb[NC+c], cwb2=cmWb[2*NC+c], cbb=cmbb[c];

  float acc[9];
  #pragma unroll
  for(int m=0;m<9;++m) acc[m]=0.f;

  for(int base64=0; base64<deg; base64+=64){
    const int nwin = (deg-base64 < 64) ? (deg-base64) : 64;

    __builtin_amdgcn_wave_barrier();
    if(lane < nwin){
      const int e   = elist[off + base64 + lane];
      const int snd = edge_ind[2*e];
      const float* yp = Y_edge + (size_t)e*9;
      float Y[9];
      #pragma unroll
      for(int m=0;m<9;++m) Y[m]=yp[m];

      float sa[9], sb[9];
      #pragma unroll
      for(int m=0;m<9;++m){ sa[m]=0.f; sb[m]=0.f; }
      cg_accum2<0>(sa, sb, wsA, wsB, Y);
      sa[0]+=b0A; sb[0]+=b0B;
      sa[0]+=kA0*Y[0];
      sa[1]+=kA1*Y[1]; sa[2]+=kA1*Y[2]; sa[3]+=kA1*Y[3];
      sa[4]+=kA2*Y[4]; sa[5]+=kA2*Y[5]; sa[6]+=kA2*Y[6]; sa[7]+=kA2*Y[7]; sa[8]+=kA2*Y[8];
      sb[0]+=kB0*Y[0];
      sb[1]+=kB1*Y[1]; sb[2]+=kB1*Y[2]; sb[3]+=kB1*Y[3];
      sb[4]+=kB2*Y[4]; sb[5]+=kB2*Y[5]; sb[6]+=kB2*Y[6]; sb[7]+=kB2*Y[7]; sb[8]+=kB2*Y[8];

      float* rp = &sRec[wv][lane*20];
      *(float4*)(rp+0)  = make_float4(sa[0],sa[1],sa[2],sa[3]);
      *(float4*)(rp+4)  = make_float4(sa[4],sa[5],sa[6],sa[7]);
      *(float4*)(rp+8)  = make_float4(sa[8],sb[0],sb[1],sb[2]);
      *(float4*)(rp+12) = make_float4(sb[3],sb[4],sb[5],sb[6]);
      *(float4*)(rp+16) = make_float4(sb[7],sb[8],__int_as_float(e),__int_as_float(snd));
    }
    __builtin_amdgcn_wave_barrier();

    for(int b8=0; b8<nwin; b8+=8){
      int e4[4], s4[4];
      const float* rp4[4];
      #pragma unroll
      for(int k=0;k<4;++k){
        int s = b8 + 4*h + k;
        int cs = (s < nwin) ? s : nwin-1;
        const float* rp = &sRec[wv][cs*20];
        rp4[k] = rp;
        e4[k] = __float_as_int(rp[18]);
        s4[k] = __float_as_int(rp[19]);
      }

      float wacc[4][14];
      #pragma unroll
      for(int k=0;k<4;++k){
        #pragma unroll
        for(int j=0;j<14;++j) wacc[k][j] = bias[j];
      }
      #pragma unroll 2
      for(int fc=0; fc<NF; fc+=4){
        float4 dv[4];
        #pragma unroll
        for(int k=0;k<4;++k) dv[k] = *(const float4*)(dist_feat + (size_t)e4[k]*NF + fc);
        #pragma unroll
        for(int df=0; df<4; ++df){
          const int f = fc + df;
          float w[14];
          #pragma unroll
          for(int q=0;q<7;++q){
            unsigned d = sWp[f][q][c];
            w[2*q]   = __uint_as_float(d << 16);
            w[2*q+1] = __uint_as_float(d & 0xffff0000u);
          }
          #pragma unroll
          for(int k=0;k<4;++k){
            float dk = (df==0)?dv[k].x:(df==1)?dv[k].y:(df==2)?dv[k].z:dv[k].w;
            #pragma unroll
            for(int j=0;j<14;++j) wacc[k][j] = fmaf(dk, w[j], wacc[k][j]);
          }
        }
      }

      #pragma unroll
      for(int k=0;k<4;++k){
        const int s = b8 + 4*h + k;
        if(s < nwin){
          const float* rp = rp4[k];
          float4 A0 = *(const float4*)(rp+0);
          float4 A1 = *(const float4*)(rp+4);
          float4 A2 = *(const float4*)(rp+8);
          float4 A3 = *(const float4*)(rp+12);
          float4 A4 = *(const float4*)(rp+16);
          const float* xp = nodes_snd + ((size_t)s4[k]*NC + c)*9;
          float x[9];
          #pragma unroll
          for(int m=0;m<9;++m) x[m]=xp[m];

          float ya[9], yb[9];
          ya[0]=fmaf(cwa0,A0.x,cba);
          ya[1]=cwa1*A0.y; ya[2]=cwa1*A0.z; ya[3]=cwa1*A0.w;
          ya[4]=cwa2*A1.x; ya[5]=cwa2*A1.y; ya[6]=cwa2*A1.z; ya[7]=cwa2*A1.w; ya[8]=cwa2*A2.x;
          yb[0]=fmaf(cwb0,A2.y,cbb);
          yb[1]=cwb1*A2.z; yb[2]=cwb1*A2.w; yb[3]=cwb1*A3.x;
          yb[4]=cwb2*A3.y; yb[5]=cwb2*A3.z; yb[6]=cwb2*A3.w; yb[7]=cwb2*A4.x; yb[8]=cwb2*A4.y;

          const float x0 = x[0];
          const float wa0 = wacc[k][0]*x0, wa1 = wacc[k][1]*x0, wa2 = wacc[k][2]*x0;
          acc[0]=fmaf(wa0,ya[0],acc[0]);
          acc[1]=fmaf(wa1,ya[1],acc[1]); acc[2]=fmaf(wa1,ya[2],acc[2]); acc[3]=fmaf(wa1,ya[3],acc[3]);
          acc[4]=fmaf(wa2,ya[4],acc[4]); acc[5]=fmaf(wa2,ya[5],acc[5]); acc[6]=fmaf(wa2,ya[6],acc[6]);
          acc[7]=fmaf(wa2,ya[7],acc[7]); acc[8]=fmaf(wa2,ya[8],acc[8]);

          cg_accum<0>(acc, &wacc[k][3], x, yb);
        }
      }
    }
  }

  #pragma unroll
  for(int m=0;m<9;++m) acc[m] += __shfl_down(acc[m], 32, 64);
  if(h == 0){
    float* op = out + ((size_t)node*NC + c)*9;
    const float* rp = nodes_rec + ((size_t)node*NC + c)*9;
    #pragma unroll
    for(int m=0;m<9;++m) op[m] = rp[m] + acc[m];
  }
}

// ---------------- launch ----------------
extern "C" void kernel_launch(void* const* d_in, const int* in_sizes, int n_in,
                              void* d_out, int out_size, void* d_ws, size_t ws_size,
                              hipStream_t stream) {
  const float* nodes_rec = (const float*)d_in[0];
  const float* nodes_snd = (const float*)d_in[1];
  const int*   edge_ind  = (const int*)  d_in[2];
  const float* Y_edge    = (const float*)d_in[3];
  const float* dist_feat = (const float*)d_in[4];
  const float* w0a=(const float*)d_in[5],  *w1a=(const float*)d_in[6],  *w2a=(const float*)d_in[7];
  const float* b0a=(const float*)d_in[8],  *ka =(const float*)d_in[9];
  const float* cmWa=(const float*)d_in[10],*cmba=(const float*)d_in[11];
  const float* w0b=(const float*)d_in[12], *w1b=(const float*)d_in[13], *w2b=(const float*)d_in[14];
  const float* b0b=(const float*)d_in[15], *kb =(const float*)d_in[16];
  const float* cmWb=(const float*)d_in[17],*cmbb=(const float*)d_in[18];
  const float* Wda=(const float*)d_in[19], *bda=(const float*)d_in[20];
  const float* Wdb=(const float*)d_in[21], *bdb=(const float*)d_in[22];
  float* out = (float*)d_out;

  char* ws = (char*)d_ws;
  int* cnt   = (int*)(ws + WS_CNT);
  int* cur   = (int*)(ws + WS_CUR);
  int* offs  = (int*)(ws + WS_OFF);
  int* elist = (int*)(ws + WS_ELIST);

  hipMemsetAsync(cnt, 0, 2*NN*sizeof(int), stream);   // cnt + cur

  hist_kernel   <<<NE/256, 256, 0, stream>>>(edge_ind, cnt);
  scan_kernel   <<<1, 1024, 0, stream>>>(cnt, offs);
  scatter_kernel<<<NE/256, 256, 0, stream>>>(edge_ind, offs, cur, elist);

  if(ws_size >= WS_NEED_BIG){
    float*        ssm = (float*)(ws + WS_SSM);
    unsigned int* msg = (unsigned int*)(ws + WS_MSG);
    selfmix_kernel<<<NE/256, 256, 0, stream>>>(Y_edge,
                                               w0a,w1a,w2a,b0a,ka,
                                               w0b,w1b,w2b,b0b,kb, ssm);
    edge_msg_kernel<<<NE/16, 256, 0, stream>>>(nodes_snd, edge_ind, dist_feat,
                                               cmWa,cmba,cmWb,cmbb,
                                               Wda,bda,Wdb,bdb, ssm, msg);
    gather_kernel  <<<NN/4, 256, 0, stream>>>(nodes_rec, cnt, offs, elist, msg, out);
  } else {
    node_kernel   <<<NN/4, 256, 0, stream>>>(nodes_rec, nodes_snd, edge_ind, Y_edge, dist_feat,
                                             w0a,w1a,w2a,b0a,ka,cmWa,cmba,
                                             w0b,w1b,w2b,b0b,kb,cmWb,cmbb,
                                             Wda,bda,Wdb,bdb,
                                             cnt, offs, elist, out);
  }
}